// Round 3
// baseline (4555.047 us; speedup 1.0000x reference)
//
#include <hip/hip_runtime.h>
#include <hip/hip_bf16.h>

typedef __hip_bfloat16 bf16;
typedef unsigned short u16;
typedef unsigned int   u32;

#define PP    4096
#define HH    32
#define NTOK  32768
#define NSTEP 60
#define NOBS  10
#define SKS   36   // LDS row stride (floats): 144B, 16B-aligned -> b128 ops; 36%32=4 bank stride

// padded fp32 weight layout (element offsets) in ws; rows padded to 36 floats
#define OFF_WIN  0        // in_proj_w  102 x 36 (cols 34,35 = 0)
#define OFF_BIN  3672     // in_proj_b  104
#define OFF_WFSA 3776     // saw@opw    32 x 36
#define OFF_BFSA 4928     // saw@opb+sab 32
#define OFF_F2W  4960     // fc2_w      32 x 32
#define OFF_F2B  5984
#define OFF_LNG  6016
#define OFF_LNB  6048
#define WGT_BYTES  (6144 * 4)

__device__ __forceinline__ float bb(bf16 v) { return __bfloat162float(v); }

// Runtime input-dtype probe on in_proj_w raw halfwords (see prior rounds).
__device__ __forceinline__ int detect_f32(const u16* raw) {
  int bad = 0;
#pragma unroll
  for (int i = 0; i < 40; i++) {
    float f = __uint_as_float(((u32)raw[2 * i]) << 16);
    bad |= !(fabsf(f) < 1.0f);
  }
  return bad;
}

__device__ __forceinline__ float rdw(const void* p, int i, int f32) {
  return f32 ? ((const float*)p)[i] : bb(((const bf16*)p)[i]);
}

// Load 32 h-values for token n (fp32 or bf16 source), vectorized.
__device__ __forceinline__ void load_h(const void* hsrc, int hf32, int n, float* he) {
  if (hf32) {
    const float4* p = (const float4*)((const float*)hsrc + (size_t)n * HH);
#pragma unroll
    for (int k = 0; k < 8; k++) {
      float4 v = p[k];
      he[4 * k] = v.x; he[4 * k + 1] = v.y; he[4 * k + 2] = v.z; he[4 * k + 3] = v.w;
    }
  } else {
    const uint4* p = (const uint4*)((const bf16*)hsrc + (size_t)n * HH);
#pragma unroll
    for (int k = 0; k < 4; k++) {
      uint4 v = p[k];
      u32 w[4] = {v.x, v.y, v.z, v.w};
#pragma unroll
      for (int m = 0; m < 4; m++) {
        he[8 * k + 2 * m]     = __uint_as_float(w[m] << 16);
        he[8 * k + 2 * m + 1] = __uint_as_float(w[m] & 0xffff0000u);
      }
    }
  }
}

// Load 8 h-values for token n at dim offset off (multiple of 8).
__device__ __forceinline__ void load_h8(const void* hsrc, int hf32, int n, int off, float* o8) {
  if (hf32) {
    const float4* p = (const float4*)((const float*)hsrc + (size_t)n * HH + off);
    float4 a = p[0], b = p[1];
    o8[0]=a.x; o8[1]=a.y; o8[2]=a.z; o8[3]=a.w;
    o8[4]=b.x; o8[5]=b.y; o8[6]=b.z; o8[7]=b.w;
  } else {
    uint4 v = *(const uint4*)((const bf16*)hsrc + (size_t)n * HH + off);
    u32 w[4] = {v.x, v.y, v.z, v.w};
#pragma unroll
    for (int m = 0; m < 4; m++) {
      o8[2 * m]     = __uint_as_float(w[m] << 16);
      o8[2 * m + 1] = __uint_as_float(w[m] & 0xffff0000u);
    }
  }
}

// outv[j] = b[rowbase+j] + W[rowbase+j] . he  for j=0..33 (fast path, padded rows)
__device__ __forceinline__ void proj34(const float* __restrict__ gw, int rowbase,
                                       const float* he, float* outv) {
#pragma unroll 2
  for (int j = 0; j < 34; j++) {
    const float4* w4 = (const float4*)(gw + OFF_WIN + (rowbase + j) * 36);
    float acc = gw[OFF_BIN + rowbase + j];
#pragma unroll
    for (int q4 = 0; q4 < 9; q4++) {
      float4 w = w4[q4];
      acc += w.x * he[4 * q4] + w.y * he[4 * q4 + 1]
           + w.z * he[4 * q4 + 2] + w.w * he[4 * q4 + 3];
    }
    outv[j] = acc;
  }
}

__device__ __forceinline__ void proj34_slow(const void* ipw, const void* ipb, int f32,
                                            int rowbase, const float* he, float* outv) {
  for (int j = 0; j < 34; j++) {
    float acc = rdw(ipb, rowbase + j, f32);
    for (int e = 0; e < 34; e++) acc += rdw(ipw, (rowbase + j) * 34 + e, f32) * he[e];
    outv[j] = acc;
  }
}

// One-shot weight prep into ws (fp32, padded rows, fc_sa@out_proj pre-fused):
// sa(av) = saw@(opw@av + opb) + sab == (saw@opw)@av + (saw@opb + sab)
__global__ void prep_kernel(const void* __restrict__ ipw, const void* __restrict__ ipb,
                            const void* __restrict__ opw, const void* __restrict__ opb,
                            const void* __restrict__ saw, const void* __restrict__ sab,
                            const void* __restrict__ f2w, const void* __restrict__ f2b,
                            const void* __restrict__ lng, const void* __restrict__ lnb,
                            float* __restrict__ gw) {
  const int f32 = detect_f32((const u16*)ipw);
  int i = blockIdx.x * blockDim.x + threadIdx.x;
  if (i < 3672) { int r = i / 36, e = i - r * 36;
    gw[OFF_WIN + i] = (e < 34) ? rdw(ipw, r * 34 + e, f32) : 0.f; return; }
  i -= 3672;
  if (i < 104)  { gw[OFF_BIN + i] = (i < 102) ? rdw(ipb, i, f32) : 0.f; return; }
  i -= 104;
  if (i < 1152) { int r = i / 36, e = i - r * 36; float a = 0.f;
    if (e < 34) for (int f = 0; f < 34; f++)
      a += rdw(saw, r * 34 + f, f32) * rdw(opw, f * 34 + e, f32);
    gw[OFF_WFSA + i] = a; return; }
  i -= 1152;
  if (i < 32)   { float a = rdw(sab, i, f32);
    for (int f = 0; f < 34; f++) a += rdw(saw, i * 34 + f, f32) * rdw(opb, f, f32);
    gw[OFF_BFSA + i] = a; return; }
  i -= 32;
  if (i < 1024) { gw[OFF_F2W + i] = rdw(f2w, i, f32); return; }
  i -= 1024;
  if (i < 32)   { gw[OFF_F2B + i] = rdw(f2b, i, f32); return; }
  i -= 32;
  if (i < 32)   { gw[OFF_LNG + i] = rdw(lng, i, f32); return; }
  i -= 32;
  if (i < 32)   { gw[OFF_LNB + i] = rdw(lnb, i, f32); return; }
}

// Fused step, v3. Block = 512 threads (8 waves), 2 output rows (128 tokens).
// Phase A: 512 threads <-> 512 proj tasks (256 tile tokens x {k,v}) -> LDS.
// Phase B: ALL 512 threads, 4 lanes per output token (quartet e/tn/i2 slicing,
// cross-lane sums via __shfl_xor within the quartet). One barrier total.
__global__ __launch_bounds__(512, 2)
void step_kernel(int t0, const void* __restrict__ x, void* __restrict__ out,
                 const float* __restrict__ gw,
                 const void* __restrict__ ipw, const void* __restrict__ ipb,
                 const void* __restrict__ opw, const void* __restrict__ opb,
                 const void* __restrict__ saw, const void* __restrict__ sab,
                 const void* __restrict__ f2w, const void* __restrict__ f2b,
                 const void* __restrict__ lng, const void* __restrict__ lnb,
                 float* __restrict__ hb0) {
  __shared__ __align__(16) float s_k[256 * SKS];
  __shared__ __align__(16) float s_v[256 * SKS];
  __shared__ __align__(16) float s_wf[32 * 36 + 32];    // fallback fused weights

  const int f32 = detect_f32((const u16*)ipw);
  const int tt = threadIdx.x;
  const int tstep = t0 + blockIdx.y;
  const int b  = blockIdx.x >> 5;
  const int r0 = (blockIdx.x & 31) << 1;

  // h source for this step
  const void* hsrc; int hf32;
  if (tstep < NOBS) {
    hsrc = f32 ? (const void*)((const float*)x + (size_t)tstep * NTOK * HH)
               : (const void*)((const bf16*)x + (size_t)tstep * NTOK * HH);
    hf32 = f32;
  } else if (f32) {  // fp32 out slots are exact rolling state
    hsrc = (const void*)((const float*)out + (size_t)(tstep - 1) * NTOK * HH); hf32 = 1;
  } else if (hb0) {  // fp32 side buffer carries exact state in bf16 mode
    hsrc = (const void*)(hb0 + (size_t)((tstep - 1) & 1) * NTOK * HH); hf32 = 1;
  } else {
    hsrc = (const void*)((const bf16*)out + (size_t)(tstep - 1) * NTOK * HH); hf32 = 0;
  }

  // Fallback: no ws -> build fused fc_sa@out_proj per block in LDS
  if (!gw) {
    for (int i = tt; i < 32 * 36 + 32; i += 512) {
      if (i < 32 * 36) {
        int r = i / 36, e = i - r * 36; float a = 0.f;
        if (e < 34) for (int f = 0; f < 34; f++)
          a += rdw(saw, r * 34 + f, f32) * rdw(opw, f * 34 + e, f32);
        s_wf[i] = a;
      } else {
        int r = i - 32 * 36; float a = rdw(sab, r, f32);
        for (int f = 0; f < 34; f++) a += rdw(saw, r * 34 + f, f32) * rdw(opb, f, f32);
        s_wf[i] = a;
      }
    }
  }

  // ---- Phase A: one k- or v-projection per thread ----
  {
    const int a_idx = tt & 255;         // tile token: tr*64+col
    const int a_half = tt >> 8;         // 0 -> k, 1 -> v
    const int tr = a_idx >> 6, col = a_idx & 63;
    int grow = r0 - 1 + tr; grow = max(0, min(63, grow));   // slot tr = clamp(r0-1+tr)
    float he[36];
    load_h(hsrc, hf32, b * PP + grow * 64 + col, he);
    he[32] = grow * (1.f / 64.f); he[33] = col * (1.f / 64.f);
    he[34] = 0.f; he[35] = 0.f;
    float kv[36];
    if (gw) proj34(gw, a_half ? 68 : 34, he, kv);
    else    proj34_slow(ipw, ipb, f32, a_half ? 68 : 34, he, kv);
    kv[34] = 0.f; kv[35] = 0.f;
    float* dst = (a_half ? s_v : s_k) + a_idx * SKS;
#pragma unroll
    for (int g = 0; g < 9; g++)
      ((float4*)dst)[g] = make_float4(kv[4*g], kv[4*g+1], kv[4*g+2], kv[4*g+3]);
  }
  __syncthreads();   // k/v tiles (and s_wf) complete — the only barrier

  // ---- Phase B: 4 lanes per output token ----
  const int tl = tt >> 2, qd = tt & 3;        // token-local id, quarter
  const int prow = r0 + (tl >> 6), pcol = tl & 63;
  const int rr = prow + (prow == 0) - (prow == 63);   // boundary shift inward
  const int cc = pcol + (pcol == 0) - (pcol == 63);
  const int np = b * PP + prow * 64 + pcol;

  // q input: always the shifted-center token (== own token when interior)
  float hq[36];
  load_h(hsrc, hf32, b * PP + rr * 64 + cc, hq);
  hq[32] = rr * (1.f / 64.f); hq[33] = cc * (1.f / 64.f);
  hq[34] = 0.f; hq[35] = 0.f;

  // residual slice of OWN token h (dims qd*8 .. qd*8+8)
  float he8[8];
  load_h8(hsrc, hf32, np, qd * 8, he8);

  // e-slices (score dim): contiguous float4 groups. j0 = 4*g0.
  const int j0 = (qd == 0) ? 0 : (qd == 1) ? 12 : (qd == 2) ? 20 : 28;
  const int nj = (qd == 0) ? 12 : 8;

  // q rows for my e-slice (rows of in_proj rowbase 0)
  float qv[12];
#pragma unroll
  for (int jj = 0; jj < 12; jj++) {
    float a = 0.f;
    const int row = j0 + jj;
    if (jj < nj && row < 34) {
      if (gw) {
        const float4* w4 = (const float4*)(gw + OFF_WIN + row * 36);
        a = gw[OFF_BIN + row];
#pragma unroll
        for (int g = 0; g < 9; g++) {
          float4 w = w4[g];
          a += w.x * hq[4*g] + w.y * hq[4*g+1] + w.z * hq[4*g+2] + w.w * hq[4*g+3];
        }
      } else {
        a = rdw(ipb, row, f32);
        for (int e = 0; e < 34; e++) a += rdw(ipw, row * 34 + e, f32) * hq[e];
      }
    }
    qv[jj] = a;
  }

  // neighbor LDS slots
  int lts[9];
#pragma unroll
  for (int dr = 0; dr < 3; dr++)
#pragma unroll
    for (int dc = 0; dc < 3; dc++)
      lts[dr * 3 + dc] = (rr - r0 + dr) * 64 + (cc - 1 + dc);

  // score partials over my e-slice, then quartet butterfly-sum
  float w9[9];
  float mx = -1e30f;
#pragma unroll
  for (int tn = 0; tn < 9; tn++) {
    const float* kp = s_k + lts[tn] * SKS + j0;
    float a = 0.f;
#pragma unroll
    for (int g = 0; g < 3; g++) {
      if (4 * g < nj) {
        float4 kk = *(const float4*)(kp + 4 * g);
        a += kk.x * qv[4*g] + kk.y * qv[4*g+1] + kk.z * qv[4*g+2] + kk.w * qv[4*g+3];
      }
    }
    float t1 = a + __shfl_xor(a, 1);
    float s  = t1 + __shfl_xor(t1, 2);
    w9[tn] = s * 0.17149858514250882f;        // 1/sqrt(34)
    mx = fmaxf(mx, w9[tn]);
  }
  float ssum = 0.f;
#pragma unroll
  for (int tn = 0; tn < 9; tn++) { w9[tn] = expf(w9[tn] - mx); ssum += w9[tn]; }
  const float inv = 1.f / ssum;
#pragma unroll
  for (int tn = 0; tn < 9; tn++) w9[tn] *= inv;

  // AV: neighbor(tn)-sliced full-width partials, quartet butterfly-sum.
  // quarter qd owns tn in {qd, qd+4, qd+8} (qd==0 gets the 3rd) — covers 0..8.
  float av[36];
#pragma unroll
  for (int e = 0; e < 36; e++) av[e] = 0.f;
  const int kt = (qd == 0) ? 3 : 2;
#pragma unroll
  for (int k = 0; k < 3; k++) {
    if (k < kt) {
      const int tn = qd + 4 * k;
      const float wv = w9[tn];
      const float* vp = s_v + lts[tn] * SKS;
#pragma unroll
      for (int g = 0; g < 9; g++) {
        float4 vv = *(const float4*)(vp + 4 * g);
        av[4*g]   += wv * vv.x; av[4*g+1] += wv * vv.y;
        av[4*g+2] += wv * vv.z; av[4*g+3] += wv * vv.w;
      }
    }
  }
#pragma unroll
  for (int e = 0; e < 34; e++) {
    float t1 = av[e] + __shfl_xor(av[e], 1);
    av[e] = t1 + __shfl_xor(t1, 2);
  }
  av[34] = 0.f; av[35] = 0.f;

  // nh for my i2-slice (i2 = qd*8+k): fused fc_sa/out_proj + residual
  float nh8[8];
#pragma unroll
  for (int k = 0; k < 8; k++) {
    const int i2 = qd * 8 + k;
    float a;
    if (gw) {
      const float4* w4 = (const float4*)(gw + OFF_WFSA + i2 * 36);
      a = gw[OFF_BFSA + i2];
#pragma unroll
      for (int g = 0; g < 9; g++) {
        float4 w = w4[g];
        a += w.x * av[4*g] + w.y * av[4*g+1] + w.z * av[4*g+2] + w.w * av[4*g+3];
      }
    } else {
      a = s_wf[32 * 36 + i2];
      const float* wr = s_wf + i2 * 36;
      for (int f = 0; f < 34; f++) a += wr[f] * av[f];
    }
    nh8[k] = he8[k] + a;
  }

  // fc2: full-width partial sums over my i2-slice, quartet butterfly-sum
  float y[32];
#pragma unroll
  for (int j = 0; j < 32; j++) {
    float a = 0.f;
    if (gw) {
      const float4* w4 = (const float4*)(gw + OFF_F2W + j * 32 + qd * 8);
      float4 wa = w4[0], wb = w4[1];
      a += wa.x * nh8[0] + wa.y * nh8[1] + wa.z * nh8[2] + wa.w * nh8[3]
         + wb.x * nh8[4] + wb.y * nh8[5] + wb.z * nh8[6] + wb.w * nh8[7];
    } else {
      for (int k = 0; k < 8; k++) a += rdw(f2w, j * 32 + qd * 8 + k, f32) * nh8[k];
    }
    y[j] = a;
  }
  float m = 0.f;
#pragma unroll
  for (int j = 0; j < 32; j++) {
    float t1 = y[j] + __shfl_xor(y[j], 1);
    y[j] = t1 + __shfl_xor(t1, 2);
    y[j] += gw ? gw[OFF_F2B + j] : rdw(f2b, j, f32);
    m += y[j];
  }
  m *= (1.f / 32.f);
  float var = 0.f;
#pragma unroll
  for (int j = 0; j < 32; j++) { float d = y[j] - m; var += d * d; }
  var *= (1.f / 32.f);
  float rstd = rsqrtf(var + 1e-5f);
  rstd = rstd * (1.5f - 0.5f * (var + 1e-5f) * rstd * rstd);  // Newton refine

  // extract my 8 outputs (static register indices, cndmask on qd) + LN + store
  float o8[8];
#pragma unroll
  for (int k = 0; k < 8; k++) {
    float v01 = (qd & 1) ? y[8 + k]  : y[k];
    float v23 = (qd & 1) ? y[24 + k] : y[16 + k];
    float vy  = (qd & 2) ? v23 : v01;
    float g  = gw ? gw[OFF_LNG + qd * 8 + k] : rdw(lng, qd * 8 + k, f32);
    float b2 = gw ? gw[OFF_LNB + qd * 8 + k] : rdw(lnb, qd * 8 + k, f32);
    o8[k] = (vy - m) * rstd * g + b2;
  }

  const size_t obase = ((size_t)tstep * NTOK + np) * HH + qd * 8;
  if (f32) {
    float4* po = (float4*)((float*)out + obase);
    po[0] = make_float4(o8[0], o8[1], o8[2], o8[3]);
    po[1] = make_float4(o8[4], o8[5], o8[6], o8[7]);
  } else {
    bf16* po = (bf16*)out + obase;
#pragma unroll
    for (int k = 0; k < 8; k++) po[k] = __float2bfloat16(o8[k]);
    if (hb0 && tstep >= NOBS - 1) {   // fp32 rolling state for next step
      float4* ph = (float4*)(hb0 + (size_t)(tstep & 1) * NTOK * HH + (size_t)np * HH + qd * 8);
      ph[0] = make_float4(o8[0], o8[1], o8[2], o8[3]);
      ph[1] = make_float4(o8[4], o8[5], o8[6], o8[7]);
    }
  }
}

extern "C" void kernel_launch(void* const* d_in, const int* in_sizes, int n_in,
                              void* d_out, int out_size, void* d_ws, size_t ws_size,
                              hipStream_t stream) {
  const void* x = d_in[0];
  float* gw  = (ws_size >= (size_t)WGT_BYTES) ? (float*)d_ws : nullptr;
  float* hb0 = (ws_size >= (size_t)WGT_BYTES + 2ull * NTOK * HH * 4)
                 ? (float*)((char*)d_ws + WGT_BYTES) : nullptr;

  if (gw)
    prep_kernel<<<24, 256, 0, stream>>>(d_in[1], d_in[2], d_in[3], d_in[4], d_in[5],
                                        d_in[6], d_in[7], d_in[8], d_in[9], d_in[10], gw);

  // Observation steps are independent: one launch, blockIdx.y = t.
  step_kernel<<<dim3(256, NOBS), 512, 0, stream>>>(0, x, d_out, gw,
                                       d_in[1], d_in[2], d_in[3], d_in[4], d_in[5],
                                       d_in[6], d_in[7], d_in[8], d_in[9], d_in[10],
                                       hb0);

  // Prediction steps are sequential.
  for (int t = NOBS; t < NSTEP; t++) {
    step_kernel<<<dim3(256, 1), 512, 0, stream>>>(t, x, d_out, gw,
                                       d_in[1], d_in[2], d_in[3], d_in[4], d_in[5],
                                       d_in[6], d_in[7], d_in[8], d_in[9], d_in[10],
                                       hb0);
  }
}

// Round 4
// 2506.758 us; speedup vs baseline: 1.8171x; 1.8171x over previous
//
#include <hip/hip_runtime.h>
#include <hip/hip_bf16.h>

typedef __hip_bfloat16 bf16;
typedef unsigned short u16;
typedef unsigned int   u32;

#define PP    4096
#define HH    32
#define NTOK  32768
#define NSTEP 60
#define NOBS  10
#define SKK   35   // k LDS row stride (floats): odd -> <=2-way bank aliasing (free)
#define SVP   33   // vp LDS row stride (floats): odd -> <=2-way bank aliasing (free)

// padded fp32 weight layout (element offsets) in ws; rows padded to 36 floats
#define OFF_WIN  0        // in_proj_w  102 x 36 (cols 34,35 = 0)
#define OFF_BIN  3672     // in_proj_b  104
#define OFF_WFSA 3776     // saw@opw    32 x 36 (kept for layout compat)
#define OFF_BFSA 4928     // saw@opb+sab 32
#define OFF_F2W  4960     // fc2_w      32 x 32
#define OFF_F2B  5984
#define OFF_LNG  6016
#define OFF_LNB  6048
#define OFF_WVP  6080     // (saw@opw)@Wv  32 x 36  (v-proj fused with fc_sa/out_proj)
#define OFF_BVP  7232     // fused v bias  32
#define WGT_FLOATS 7264
#define WGT_BYTES  (7296 * 4)

__device__ __forceinline__ float bb(bf16 v) { return __bfloat162float(v); }

// Runtime input-dtype probe on in_proj_w raw halfwords (see prior rounds).
__device__ __forceinline__ int detect_f32(const u16* raw) {
  int bad = 0;
#pragma unroll
  for (int i = 0; i < 40; i++) {
    float f = __uint_as_float(((u32)raw[2 * i]) << 16);
    bad |= !(fabsf(f) < 1.0f);
  }
  return bad;
}

__device__ __forceinline__ float rdw(const void* p, int i, int f32) {
  return f32 ? ((const float*)p)[i] : bb(((const bf16*)p)[i]);
}

// Load 32 h-values for token n (fp32 or bf16 source), vectorized, static idx.
__device__ __forceinline__ void load_h(const void* hsrc, int hf32, int n, float* he) {
  if (hf32) {
    const float4* p = (const float4*)((const float*)hsrc + (size_t)n * HH);
#pragma unroll
    for (int k = 0; k < 8; k++) {
      float4 v = p[k];
      he[4 * k] = v.x; he[4 * k + 1] = v.y; he[4 * k + 2] = v.z; he[4 * k + 3] = v.w;
    }
  } else {
    const uint4* p = (const uint4*)((const bf16*)hsrc + (size_t)n * HH);
#pragma unroll
    for (int k = 0; k < 4; k++) {
      uint4 v = p[k];
      u32 w[4] = {v.x, v.y, v.z, v.w};
#pragma unroll
      for (int m = 0; m < 4; m++) {
        he[8 * k + 2 * m]     = __uint_as_float(w[m] << 16);
        he[8 * k + 2 * m + 1] = __uint_as_float(w[m] & 0xffff0000u);
      }
    }
  }
}

// Load 8 h-values for token n at dim offset off (multiple of 8), static idx.
__device__ __forceinline__ void load_h8(const void* hsrc, int hf32, int n, int off, float* o8) {
  if (hf32) {
    const float4* p = (const float4*)((const float*)hsrc + (size_t)n * HH + off);
    float4 a = p[0], b = p[1];
    o8[0]=a.x; o8[1]=a.y; o8[2]=a.z; o8[3]=a.w;
    o8[4]=b.x; o8[5]=b.y; o8[6]=b.z; o8[7]=b.w;
  } else {
    uint4 v = *(const uint4*)((const bf16*)hsrc + (size_t)n * HH + off);
    u32 w[4] = {v.x, v.y, v.z, v.w};
#pragma unroll
    for (int m = 0; m < 4; m++) {
      o8[2 * m]     = __uint_as_float(w[m] << 16);
      o8[2 * m + 1] = __uint_as_float(w[m] & 0xffff0000u);
    }
  }
}

// One-shot weight prep into ws. New: Wvp/bvp fold fc_sa@out_proj INTO the
// v-projection:  sa(out(av)) = (saw@opw)@av + (saw@opb+sab);  av = sum w*v,
// v = Wv h + bv  =>  contribution = sum_tn w_tn * (Wvp h_tn + bvp), since
// sum w_tn = 1 the bias folds into each stored vp row.
__global__ void prep_kernel(const void* __restrict__ ipw, const void* __restrict__ ipb,
                            const void* __restrict__ opw, const void* __restrict__ opb,
                            const void* __restrict__ saw, const void* __restrict__ sab,
                            const void* __restrict__ f2w, const void* __restrict__ f2b,
                            const void* __restrict__ lng, const void* __restrict__ lnb,
                            float* __restrict__ gw) {
  const int f32 = detect_f32((const u16*)ipw);
  int i = blockIdx.x * blockDim.x + threadIdx.x;
  if (i < 3672) { int r = i / 36, e = i - r * 36;
    gw[OFF_WIN + i] = (e < 34) ? rdw(ipw, r * 34 + e, f32) : 0.f; return; }
  i -= 3672;
  if (i < 104)  { gw[OFF_BIN + i] = (i < 102) ? rdw(ipb, i, f32) : 0.f; return; }
  i -= 104;
  if (i < 1152) { int r = i / 36, e = i - r * 36; float a = 0.f;
    if (e < 34) for (int f = 0; f < 34; f++)
      a += rdw(saw, r * 34 + f, f32) * rdw(opw, f * 34 + e, f32);
    gw[OFF_WFSA + i] = a; return; }
  i -= 1152;
  if (i < 32)   { float a = rdw(sab, i, f32);
    for (int f = 0; f < 34; f++) a += rdw(saw, i * 34 + f, f32) * rdw(opb, f, f32);
    gw[OFF_BFSA + i] = a; return; }
  i -= 32;
  if (i < 1024) { gw[OFF_F2W + i] = rdw(f2w, i, f32); return; }
  i -= 1024;
  if (i < 32)   { gw[OFF_F2B + i] = rdw(f2b, i, f32); return; }
  i -= 32;
  if (i < 32)   { gw[OFF_LNG + i] = rdw(lng, i, f32); return; }
  i -= 32;
  if (i < 32)   { gw[OFF_LNB + i] = rdw(lnb, i, f32); return; }
  i -= 32;
  if (i < 1152) {            // Wvp[r][e] = sum_f WFSA[r][f] * Wv[f][e]
    int r = i / 36, e = i - r * 36; float a = 0.f;
    if (e < 34) {
      for (int f = 0; f < 34; f++) {
        float wf = 0.f;
        for (int g = 0; g < 34; g++)
          wf += rdw(saw, r * 34 + g, f32) * rdw(opw, g * 34 + f, f32);
        a += wf * rdw(ipw, (68 + f) * 34 + e, f32);
      }
    }
    gw[OFF_WVP + i] = a; return; }
  i -= 1152;
  if (i < 32) {              // bvp[r] = BFSA[r] + sum_f WFSA[r][f] * bv[f]
    float a = rdw(sab, i, f32);
    for (int g = 0; g < 34; g++) a += rdw(saw, i * 34 + g, f32) * rdw(opb, g, f32);
    for (int f = 0; f < 34; f++) {
      float wf = 0.f;
      for (int g = 0; g < 34; g++)
        wf += rdw(saw, i * 34 + g, f32) * rdw(opw, g * 34 + f, f32);
      a += wf * rdw(ipb, 68 + f, f32);
    }
    gw[OFF_BVP + i] = a; return; }
}

// Fused step, v4. Block = 512 threads (8 waves), 2 output rows (128 tokens).
// Phase A: t<256 -> k(token t) to s_k; t>=256 -> fused vp(token t-256) to s_vp.
//   All projection loops FULLY unrolled, rows written straight to LDS
//   (no runtime-indexed private arrays -> no scratch traffic).
// Phase B: all 512 threads, 4 lanes/token: q e-sliced (9/9/8/8), scores via
//   quartet __shfl_xor butterfly; nh/fc2 i2-sliced; LDS reads are b32 at odd
//   stride (conflict-free).
__global__ __launch_bounds__(512, 4)
void step_kernel(int t0, const void* __restrict__ x, void* __restrict__ out,
                 const float* __restrict__ gw,
                 const void* __restrict__ ipw, const void* __restrict__ ipb,
                 const void* __restrict__ opw, const void* __restrict__ opb,
                 const void* __restrict__ saw, const void* __restrict__ sab,
                 const void* __restrict__ f2w, const void* __restrict__ f2b,
                 const void* __restrict__ lng, const void* __restrict__ lnb,
                 float* __restrict__ hb0) {
  __shared__ float s_k [256 * SKK];          // 35840 B, k rows WITH bias
  __shared__ float s_vp[256 * SVP];          // 33792 B, fused vp rows WITH bias
  __shared__ float s_wvp[32 * 36 + 32];      // fallback fused v weights

  const int f32 = detect_f32((const u16*)ipw);
  const int tt = threadIdx.x;
  const int tstep = t0 + blockIdx.y;
  const int b  = blockIdx.x >> 5;
  const int r0 = (blockIdx.x & 31) << 1;

  // h source for this step
  const void* hsrc; int hf32;
  if (tstep < NOBS) {
    hsrc = f32 ? (const void*)((const float*)x + (size_t)tstep * NTOK * HH)
               : (const void*)((const bf16*)x + (size_t)tstep * NTOK * HH);
    hf32 = f32;
  } else if (f32) {  // fp32 out slots are exact rolling state
    hsrc = (const void*)((const float*)out + (size_t)(tstep - 1) * NTOK * HH); hf32 = 1;
  } else if (hb0) {  // fp32 side buffer carries exact state in bf16 mode
    hsrc = (const void*)(hb0 + (size_t)((tstep - 1) & 1) * NTOK * HH); hf32 = 1;
  } else {
    hsrc = (const void*)((const bf16*)out + (size_t)(tstep - 1) * NTOK * HH); hf32 = 0;
  }

  // Fallback: no ws -> build fused Wvp/bvp per block in LDS (then barrier).
  if (!gw) {
    for (int i = tt; i < 32 * 36 + 32; i += 512) {
      if (i < 32 * 36) {
        int r = i / 36, e = i - r * 36; float a = 0.f;
        if (e < 34) {
          for (int f = 0; f < 34; f++) {
            float wf = 0.f;
            for (int g = 0; g < 34; g++)
              wf += rdw(saw, r * 34 + g, f32) * rdw(opw, g * 34 + f, f32);
            a += wf * rdw(ipw, (68 + f) * 34 + e, f32);
          }
        }
        s_wvp[i] = a;
      } else {
        int r = i - 32 * 36;
        float a = rdw(sab, r, f32);
        for (int g = 0; g < 34; g++) a += rdw(saw, r * 34 + g, f32) * rdw(opb, g, f32);
        for (int f = 0; f < 34; f++) {
          float wf = 0.f;
          for (int g = 0; g < 34; g++)
            wf += rdw(saw, r * 34 + g, f32) * rdw(opw, g * 34 + f, f32);
          a += wf * rdw(ipb, 68 + f, f32);
        }
        s_wvp[i] = a;
      }
    }
    __syncthreads();   // gw is uniform -> barrier uniform
  }

  // ---- Phase A: one projection per thread, rows written straight to LDS ----
  {
    const int a_idx = tt & 255;         // tile token: tr*64+col
    const int a_half = tt >> 8;         // 0 -> k, 1 -> vp
    const int tr = a_idx >> 6, col = a_idx & 63;
    int grow = r0 - 1 + tr; grow = max(0, min(63, grow));   // slot tr = clamp(r0-1+tr)
    float he[36];
    load_h(hsrc, hf32, b * PP + grow * 64 + col, he);
    he[32] = grow * (1.f / 64.f); he[33] = col * (1.f / 64.f);
    he[34] = 0.f; he[35] = 0.f;

    if (a_half == 0) {
      float* dst = s_k + a_idx * SKK;
      if (gw) {
#pragma unroll
        for (int j = 0; j < 34; j++) {
          const float4* w4 = (const float4*)(gw + OFF_WIN + (34 + j) * 36);
          float acc = gw[OFF_BIN + 34 + j];
#pragma unroll
          for (int g = 0; g < 9; g++) {
            float4 w = w4[g];
            acc += w.x * he[4*g] + w.y * he[4*g+1] + w.z * he[4*g+2] + w.w * he[4*g+3];
          }
          dst[j] = acc;
        }
      } else {
        for (int j = 0; j < 34; j++) {
          float acc = rdw(ipb, 34 + j, f32);
          for (int e = 0; e < 34; e++) acc += rdw(ipw, (34 + j) * 34 + e, f32) * he[e];
          dst[j] = acc;
        }
      }
    } else {
      float* dst = s_vp + a_idx * SVP;
      if (gw) {
#pragma unroll
        for (int j = 0; j < 32; j++) {
          const float4* w4 = (const float4*)(gw + OFF_WVP + j * 36);
          float acc = gw[OFF_BVP + j];
#pragma unroll
          for (int g = 0; g < 9; g++) {
            float4 w = w4[g];
            acc += w.x * he[4*g] + w.y * he[4*g+1] + w.z * he[4*g+2] + w.w * he[4*g+3];
          }
          dst[j] = acc;
        }
      } else {
        for (int j = 0; j < 32; j++) {
          float acc = s_wvp[32 * 36 + j];
          const float* wr = s_wvp + j * 36;
          for (int e = 0; e < 34; e++) acc += wr[e] * he[e];
          dst[j] = acc;
        }
      }
    }
  }
  __syncthreads();   // k/vp tiles complete — the only fast-path barrier

  // ---- Phase B: 4 lanes per output token ----
  const int tl = tt >> 2, qd = tt & 3;        // token-local id, quarter
  const int prow = r0 + (tl >> 6), pcol = tl & 63;
  const int rr = prow + (prow == 0) - (prow == 63);   // boundary shift inward
  const int cc = pcol + (pcol == 0) - (pcol == 63);
  const int np = b * PP + prow * 64 + pcol;

  // q e-slice: {0-8},{9-17},{18-25},{26-33}
  const int e0 = (qd < 2) ? qd * 9 : 18 + (qd - 2) * 8;
  const int ne = (qd < 2) ? 9 : 8;

  // q input: shifted-center token (== own token when interior)
  float hq[36];
  load_h(hsrc, hf32, b * PP + rr * 64 + cc, hq);
  hq[32] = rr * (1.f / 64.f); hq[33] = cc * (1.f / 64.f);
  hq[34] = 0.f; hq[35] = 0.f;

  // q rows for my e-slice (fully unrolled, static register indices)
  float q[9];
#pragma unroll
  for (int jj = 0; jj < 9; jj++) {
    float a = 0.f;
    if (jj < ne) {
      const int row = e0 + jj;
      if (gw) {
        const float4* w4 = (const float4*)(gw + OFF_WIN + row * 36);
        a = gw[OFF_BIN + row];
#pragma unroll
        for (int g = 0; g < 9; g++) {
          float4 w = w4[g];
          a += w.x * hq[4*g] + w.y * hq[4*g+1] + w.z * hq[4*g+2] + w.w * hq[4*g+3];
        }
      } else {
        a = rdw(ipb, row, f32);
        for (int e = 0; e < 34; e++) a += rdw(ipw, row * 34 + e, f32) * hq[e];
      }
    }
    q[jj] = a;
  }

  // neighbor LDS slots
  int lts[9];
#pragma unroll
  for (int dr = 0; dr < 3; dr++)
#pragma unroll
    for (int dc = 0; dc < 3; dc++)
      lts[dr * 3 + dc] = (rr - r0 + dr) * 64 + (cc - 1 + dc);

  // scores: partial dot over my e-slice (b32 LDS reads), quartet butterfly-sum
  float w9[9];
  float mx = -1e30f;
#pragma unroll
  for (int tn = 0; tn < 9; tn++) {
    const float* kp = s_k + lts[tn] * SKK + e0;
    float a = 0.f;
#pragma unroll
    for (int jj = 0; jj < 9; jj++)
      if (jj < ne) a += q[jj] * kp[jj];
    a += __shfl_xor(a, 1);
    a += __shfl_xor(a, 2);
    w9[tn] = a * 0.17149858514250882f;        // 1/sqrt(34)
    mx = fmaxf(mx, w9[tn]);
  }
  float ssum = 0.f;
#pragma unroll
  for (int tn = 0; tn < 9; tn++) { w9[tn] = expf(w9[tn] - mx); ssum += w9[tn]; }
  const float inv = 1.f / ssum;
#pragma unroll
  for (int tn = 0; tn < 9; tn++) w9[tn] *= inv;

  // residual slice of OWN token h (dims qd*8 .. qd*8+8)
  float he8[8];
  load_h8(hsrc, hf32, np, qd * 8, he8);

  // nh slice: he8 + sum_tn w9 * vp[tn][qd*8..]; bvp already folded into vp rows
  float nh8[8];
#pragma unroll
  for (int k = 0; k < 8; k++) nh8[k] = he8[k];
#pragma unroll
  for (int tn = 0; tn < 9; tn++) {
    const float wv = w9[tn];
    const float* vp = s_vp + lts[tn] * SVP + qd * 8;
#pragma unroll
    for (int k = 0; k < 8; k++) nh8[k] += wv * vp[k];
  }

  // fc2: per-lane partial over my i2-slice, quartet butterfly-sum, +bias
  float y[32];
#pragma unroll
  for (int j = 0; j < 32; j++) {
    float a;
    if (gw) {
      const float4* w4 = (const float4*)(gw + OFF_F2W + j * 32 + qd * 8);
      float4 wa = w4[0], wb = w4[1];
      a = wa.x * nh8[0] + wa.y * nh8[1] + wa.z * nh8[2] + wa.w * nh8[3]
        + wb.x * nh8[4] + wb.y * nh8[5] + wb.z * nh8[6] + wb.w * nh8[7];
    } else {
      a = 0.f;
      for (int k2 = 0; k2 < 8; k2++) a += rdw(f2w, j * 32 + qd * 8 + k2, f32) * nh8[k2];
    }
    a += __shfl_xor(a, 1);
    a += __shfl_xor(a, 2);
    y[j] = a + (gw ? gw[OFF_F2B + j] : rdw(f2b, j, f32));
  }

  float m = 0.f;
#pragma unroll
  for (int j = 0; j < 32; j++) m += y[j];
  m *= (1.f / 32.f);
  float var = 0.f;
#pragma unroll
  for (int j = 0; j < 32; j++) { float d = y[j] - m; var += d * d; }
  var *= (1.f / 32.f);
  float rstd = rsqrtf(var + 1e-5f);
  rstd = rstd * (1.5f - 0.5f * (var + 1e-5f) * rstd * rstd);  // Newton refine

  // extract my 8 outputs (static register indices, cndmask on qd) + LN
  float o8[8];
#pragma unroll
  for (int k = 0; k < 8; k++) {
    float v01 = (qd & 1) ? y[8 + k]  : y[k];
    float v23 = (qd & 1) ? y[24 + k] : y[16 + k];
    float vy  = (qd & 2) ? v23 : v01;
    float g  = gw ? gw[OFF_LNG + qd * 8 + k] : rdw(lng, qd * 8 + k, f32);
    float b2 = gw ? gw[OFF_LNB + qd * 8 + k] : rdw(lnb, qd * 8 + k, f32);
    o8[k] = (vy - m) * rstd * g + b2;
  }

  const size_t obase = ((size_t)tstep * NTOK + np) * HH + qd * 8;
  if (f32) {
    float4* po = (float4*)((float*)out + obase);
    po[0] = make_float4(o8[0], o8[1], o8[2], o8[3]);
    po[1] = make_float4(o8[4], o8[5], o8[6], o8[7]);
  } else {
    u32 pk[4];
#pragma unroll
    for (int k2 = 0; k2 < 4; k2++) {
      bf16 b0 = __float2bfloat16(o8[2 * k2]);
      bf16 b1 = __float2bfloat16(o8[2 * k2 + 1]);
      pk[k2] = (u32)*reinterpret_cast<u16*>(&b0)
             | ((u32)*reinterpret_cast<u16*>(&b1) << 16);
    }
    *(uint4*)((bf16*)out + obase) = make_uint4(pk[0], pk[1], pk[2], pk[3]);
    if (hb0 && tstep >= NOBS - 1) {   // fp32 rolling state for next step
      float4* ph = (float4*)(hb0 + (size_t)(tstep & 1) * NTOK * HH + (size_t)np * HH + qd * 8);
      ph[0] = make_float4(o8[0], o8[1], o8[2], o8[3]);
      ph[1] = make_float4(o8[4], o8[5], o8[6], o8[7]);
    }
  }
}

extern "C" void kernel_launch(void* const* d_in, const int* in_sizes, int n_in,
                              void* d_out, int out_size, void* d_ws, size_t ws_size,
                              hipStream_t stream) {
  const void* x = d_in[0];
  float* gw  = (ws_size >= (size_t)WGT_BYTES) ? (float*)d_ws : nullptr;
  float* hb0 = (ws_size >= (size_t)WGT_BYTES + 2ull * NTOK * HH * 4)
                 ? (float*)((char*)d_ws + WGT_BYTES) : nullptr;

  if (gw)
    prep_kernel<<<29, 256, 0, stream>>>(d_in[1], d_in[2], d_in[3], d_in[4], d_in[5],
                                        d_in[6], d_in[7], d_in[8], d_in[9], d_in[10], gw);

  // Observation steps are independent: one launch, blockIdx.y = t.
  step_kernel<<<dim3(256, NOBS), 512, 0, stream>>>(0, x, d_out, gw,
                                       d_in[1], d_in[2], d_in[3], d_in[4], d_in[5],
                                       d_in[6], d_in[7], d_in[8], d_in[9], d_in[10],
                                       hb0);

  // Prediction steps are sequential.
  for (int t = NOBS; t < NSTEP; t++) {
    step_kernel<<<dim3(256, 1), 512, 0, stream>>>(t, x, d_out, gw,
                                       d_in[1], d_in[2], d_in[3], d_in[4], d_in[5],
                                       d_in[6], d_in[7], d_in[8], d_in[9], d_in[10],
                                       hb0);
  }
}